// Round 4
// baseline (351.025 us; speedup 1.0000x reference)
//
#include <hip/hip_runtime.h>
#include <hip/hip_cooperative_groups.h>
#include <hip/hip_bf16.h>
#include <math.h>

namespace cg = cooperative_groups;

// Problem dims (fixed by setup_inputs): B=64 samples, N=512 spins/flips, H=2048 hidden
constexpr int NB = 64;
constexpr int NN = 512;
constexpr int NH = 2048;
constexpr float LN2 = 0.6931471805599453f;
constexpr int GRID = 512;   // 2 blocks/CU co-resident (LDS 33KB, <=256 VGPR)

// Workspace layout (floats)
constexpr size_t OFF_T2  = 0;                          // t2[k][h]=tanh(2W)      : 512*2048
constexpr size_t OFF_LC  = OFF_T2  + (size_t)NN*NH;    // LC[k]=sum lncosh(2W)   : 512
constexpr size_t OFF_XT  = OFF_LC  + NN;               // xt[n][b]=x[b][n]       : 512*64
constexpr size_t OFF_TT  = OFF_XT  + (size_t)NN*NB;    // Tt[h][b]=tanh(theta)   : 2048*64
constexpr size_t OFF_THP = OFF_TT  + (size_t)NH*NB;    // thp[nc][b][h] partials : 16*64*2048
constexpr size_t OFF_DS  = OFF_THP + (size_t)16*NB*NH; // dsum[hc][k][b]         : 16*512*64

__global__ __launch_bounds__(256, 2) void k_fused(const float* __restrict__ W,
                                                  const float* __restrict__ x,
                                                  const float* __restrict__ bvec,
                                                  const float* __restrict__ a,
                                                  const float* __restrict__ Oxy,
                                                  float* __restrict__ out,
                                                  float* __restrict__ ws) {
    cg::grid_group grid = cg::this_grid();
    __shared__ float Tl[128 * NB];     // 32 KB slab: T[h0..h0+128)[all b], [h][b] layout
    __shared__ float red[256];

    float* t2   = ws + OFF_T2;
    float* LC   = ws + OFF_LC;
    float* xt   = ws + OFF_XT;
    float* Tt   = ws + OFF_TT;
    float* thp  = ws + OFF_THP;
    float* dsum = ws + OFF_DS;

    int bid = blockIdx.x, tid = threadIdx.x;

    // ================= S0: t2/LC row (1 W-row per block) + xt transpose =====
    {
        int k = bid;
        const float4* wr = (const float4*)(W + (size_t)k * NH);
        float4* tr = (float4*)(t2 + (size_t)k * NH);
        float4 w0 = wr[tid], w1 = wr[tid + 256];       // both loads in flight
        float in[8] = {w0.x, w0.y, w0.z, w0.w, w1.x, w1.y, w1.z, w1.w};
        float t[8], lsum = 0.f;
#pragma unroll
        for (int i = 0; i < 8; i++) {
            float y  = 2.0f * in[i];
            float ay = fabsf(y);
            float e  = __expf(-2.0f * ay);
            t[i] = copysignf((1.0f - e) / (1.0f + e), y);
            lsum += ay + __logf(1.0f + e) - LN2;       // lncosh(y)
        }
        tr[tid]       = make_float4(t[0], t[1], t[2], t[3]);
        tr[tid + 256] = make_float4(t[4], t[5], t[6], t[7]);
        red[tid] = lsum; __syncthreads();
        for (int s = 128; s > 0; s >>= 1) {
            if (tid < s) red[tid] += red[tid + s];
            __syncthreads();
        }
        if (tid == 0) LC[k] = red[0];
        // xt transpose: 1 elem per thread
        int idx = bid * 256 + tid;                     // idx = n*64 + b
        int b = idx & 63, n = idx >> 6;
        xt[idx] = x[(size_t)b * NN + n];
    }
    grid.sync();

    // ================= S1: split-K GEMM partial (1 item per block) ==========
    {
        int nc = bid & 15;             // 16 n-chunks of 32
        int bt = (bid >> 4) & 3;       // 4 b-tiles of 16
        int ht = bid >> 6;             // 8 h-tiles of 256
        int h  = ht * 256 + tid;
        float acc[16];
#pragma unroll
        for (int j = 0; j < 16; j++) acc[j] = 0.f;
        const float* xp = xt + (size_t)nc * 32 * NB + bt * 16;  // uniform -> s_load_dwordx16
        const float* wp = W + (size_t)(nc * 32) * NH + h;
#pragma unroll 4
        for (int n = 0; n < 32; n++) {
            float w = wp[(size_t)n * NH];
#pragma unroll
            for (int j = 0; j < 16; j++) acc[j] = fmaf(xp[n * NB + j], w, acc[j]);
        }
        float* op = thp + (size_t)nc * NB * NH + (size_t)(bt * 16) * NH + h;
#pragma unroll
        for (int j = 0; j < 16; j++) op[(size_t)j * NH] = acc[j];
    }
    grid.sync();

    // ================= S1b: reduce 16 partials + bias + tanh -> Tt[h][b] ====
    {
        int g = bid * 256 + tid;       // g = b*2048 + h
        int b = g >> 11, h = g & (NH - 1);
        float th = bvec[h];
#pragma unroll
        for (int nc = 0; nc < 16; nc++) th += thp[(size_t)nc * NB * NH + g];
        float ay = fabsf(th);
        float e  = __expf(-2.0f * ay);
        Tt[(size_t)h * NB + b] = copysignf((1.0f - e) / (1.0f + e), th);
    }
    grid.sync();

    // ================= S2: flip loop, 1 tile (16 k x 128 h) per block =======
    {
        int hc = bid & 15;             // 16 h-chunks of 128
        int kt = bid >> 4;             // 32 k-tiles of 16
        const float4* src = (const float4*)(Tt + (size_t)hc * 128 * NB);
        float4* dst = (float4*)Tl;
#pragma unroll
        for (int i = 0; i < 8; i++) dst[tid + i * 256] = src[tid + i * 256];
        __syncthreads();

        int wv = tid >> 6, lane = tid & 63;
        int kb = __builtin_amdgcn_readfirstlane(kt * 16 + wv * 4);  // SGPR base
        float ms[4];
        const float* rr[4];
#pragma unroll
        for (int j = 0; j < 4; j++) {
            ms[j] = -xt[(size_t)(kb + j) * NB + lane];
            rr[j] = t2 + (size_t)(kb + j) * NH + hc * 128;
        }
        float lp[4] = {0.f, 0.f, 0.f, 0.f};
        for (int h0 = 0; h0 < 128; h0 += 32) {
            float p[4] = {1.f, 1.f, 1.f, 1.f};
#pragma unroll
            for (int hh = 0; hh < 32; hh++) {
                int h = h0 + hh;
                float T = Tl[h * NB + lane];      // lanes stride-1: conflict-free
#pragma unroll
                for (int j = 0; j < 4; j++)
                    p[j] *= fmaf(rr[j][h] * T, ms[j], 1.0f);  // 1 - s*T*tanh(2W)
            }
#pragma unroll
            for (int j = 0; j < 4; j++) lp[j] += __logf(p[j]);
        }
#pragma unroll
        for (int j = 0; j < 4; j++)
            dsum[(size_t)hc * NN * NB + (size_t)(kb + j) * NB + lane] = lp[j];
    }
    grid.sync();

    // ================= S3: out[b] reduction (blocks 0..63) ==================
    if (bid < NB) {
        int b = bid;
        float sum = 0.f;
        for (int k = tid; k < NN; k += 256) {
            float d = LC[k] - 2.0f * xt[(size_t)k * NB + b] * a[k];
#pragma unroll
            for (int hc = 0; hc < 16; hc++)
                d += dsum[(size_t)hc * NN * NB + (size_t)k * NB + b];
            sum += Oxy[k] * __expf(d);
        }
        red[tid] = sum; __syncthreads();
        for (int s = 128; s > 0; s >>= 1) {
            if (tid < s) red[tid] += red[tid + s];
            __syncthreads();
        }
        if (tid == 0) out[b] = red[0];
    }
}

extern "C" void kernel_launch(void* const* d_in, const int* in_sizes, int n_in,
                              void* d_out, int out_size, void* d_ws, size_t ws_size,
                              hipStream_t stream) {
    const float* W    = (const float*)d_in[1];
    const float* x    = (const float*)d_in[0];
    const float* bvec = (const float*)d_in[2];
    const float* a    = (const float*)d_in[3];
    const float* Oxy  = (const float*)d_in[4];
    float* out = (float*)d_out;
    float* ws  = (float*)d_ws;

    void* args[] = {(void*)&W, (void*)&x, (void*)&bvec, (void*)&a,
                    (void*)&Oxy, (void*)&out, (void*)&ws};
    hipLaunchCooperativeKernel((void*)k_fused, dim3(GRID), dim3(256), args, 0, stream);
}

// Round 5
// 93.865 us; speedup vs baseline: 3.7397x; 3.7397x over previous
//
#include <hip/hip_runtime.h>
#include <hip/hip_bf16.h>
#include <math.h>

// Problem dims (fixed by setup_inputs): B=64 samples, N=512 spins/flips, H=2048 hidden
constexpr int NB = 64;
constexpr int NN = 512;
constexpr int NH = 2048;
constexpr float LN2 = 0.6931471805599453f;

// Workspace layout (floats)
constexpr size_t OFF_T2 = 0;                        // t2[k][h]=tanh(2W)      : 512*2048
constexpr size_t OFF_LC = OFF_T2 + (size_t)NN*NH;   // LC[k]=sum lncosh(2W)   : 512
constexpr size_t OFF_TT = OFF_LC + NN;              // Tt[h][b]=tanh(theta)   : 2048*64

// ===== D1: mixed-role. blocks [0,512): t2/LC row k. blocks [512,640): GEMM+tanh -> Tt.
__global__ __launch_bounds__(512) void k_prep(const float* __restrict__ W,
                                              const float* __restrict__ x,
                                              const float* __restrict__ bvec,
                                              float* __restrict__ t2,
                                              float* __restrict__ LC,
                                              float* __restrict__ Tt,
                                              float* __restrict__ out) {
    __shared__ float sm[10240];            // 40 KB, role-dependent use
    int bid = blockIdx.x, tid = threadIdx.x;
    if (bid < NN) {                        // ---------- t2 / LC role ----------
        int k = bid;
        const float4* wr = (const float4*)(W + (size_t)k * NH);
        float4* tr = (float4*)(t2 + (size_t)k * NH);
        float4 w0 = wr[tid];
        float in[4] = {w0.x, w0.y, w0.z, w0.w};
        float t[4], lsum = 0.f;
#pragma unroll
        for (int i = 0; i < 4; i++) {
            float y  = 2.0f * in[i];
            float ay = fabsf(y);
            float e  = __expf(-2.0f * ay);
            t[i] = copysignf((1.0f - e) / (1.0f + e), y);
            lsum += ay + __logf(1.0f + e) - LN2;       // lncosh(y)
        }
        tr[tid] = make_float4(t[0], t[1], t[2], t[3]);
        sm[tid] = lsum; __syncthreads();
        for (int s = 256; s > 0; s >>= 1) {
            if (tid < s) sm[tid] += sm[tid + s];
            __syncthreads();
        }
        if (tid == 0) LC[k] = sm[0];
    } else {                               // ---------- GEMM + tanh role ----------
        int gb = bid - NN;                 // 0..127
        int ht = gb & 31;                  // 32 h-tiles of 64
        int bt = gb >> 5;                  // 4 b-tiles of 16
        // transpose x slice into LDS: xs[n][j], row stride 20 floats (80B, 16B-aligned)
        {
            int j = tid >> 5, c = tid & 31;                    // 16 rows x 32 cols
            const float4* xr = (const float4*)(x + (size_t)(bt * 16 + j) * NN);
#pragma unroll
            for (int i = 0; i < 4; i++) {
                float4 v = xr[c + i * 32];
                int n0 = (c + i * 32) * 4;
                sm[(n0 + 0) * 20 + j] = v.x;
                sm[(n0 + 1) * 20 + j] = v.y;
                sm[(n0 + 2) * 20 + j] = v.z;
                sm[(n0 + 3) * 20 + j] = v.w;
            }
        }
        __syncthreads();
        int hl = tid & 63, ns = tid >> 6;  // 8 n-segments of 64
        int h  = ht * 64 + hl;
        float acc[16];
#pragma unroll
        for (int j = 0; j < 16; j++) acc[j] = 0.f;
        const float* wp = W + h;
#pragma unroll 4
        for (int n = ns * 64; n < ns * 64 + 64; n++) {
            float w = wp[(size_t)n * NH];                      // coalesced 256B/wave
            const float4* xv = (const float4*)(sm + n * 20);   // wave-uniform -> broadcast
            float4 a0 = xv[0], a1 = xv[1], a2 = xv[2], a3 = xv[3];
            acc[0]  = fmaf(a0.x, w, acc[0]);  acc[1]  = fmaf(a0.y, w, acc[1]);
            acc[2]  = fmaf(a0.z, w, acc[2]);  acc[3]  = fmaf(a0.w, w, acc[3]);
            acc[4]  = fmaf(a1.x, w, acc[4]);  acc[5]  = fmaf(a1.y, w, acc[5]);
            acc[6]  = fmaf(a1.z, w, acc[6]);  acc[7]  = fmaf(a1.w, w, acc[7]);
            acc[8]  = fmaf(a2.x, w, acc[8]);  acc[9]  = fmaf(a2.y, w, acc[9]);
            acc[10] = fmaf(a2.z, w, acc[10]); acc[11] = fmaf(a2.w, w, acc[11]);
            acc[12] = fmaf(a3.x, w, acc[12]); acc[13] = fmaf(a3.y, w, acc[13]);
            acc[14] = fmaf(a3.z, w, acc[14]); acc[15] = fmaf(a3.w, w, acc[15]);
        }
        __syncthreads();                   // xs no longer needed; reuse sm for reduce
        float4* r4 = (float4*)sm;          // red[ns][hl][16] = 32KB
#pragma unroll
        for (int q = 0; q < 4; q++)
            r4[(ns * 1024 + hl * 16) / 4 + q] =
                make_float4(acc[q*4], acc[q*4+1], acc[q*4+2], acc[q*4+3]);
        __syncthreads();
#pragma unroll
        for (int o = tid; o < 1024; o += 512) {
            int hl2 = o >> 4, j2 = o & 15;
            float th = bvec[ht * 64 + hl2];
#pragma unroll
            for (int n2 = 0; n2 < 8; n2++) th += sm[n2 * 1024 + hl2 * 16 + j2];
            float ay = fabsf(th);
            float e  = __expf(-2.0f * ay);
            Tt[(size_t)(ht * 64 + hl2) * NB + bt * 16 + j2] =
                copysignf((1.0f - e) / (1.0f + e), th);
        }
        if (gb == 0 && tid < NB) out[tid] = 0.f;   // zero out before D2's atomics
    }
}

// ===== D2: 256 blocks x 512 thr; block owns k0=2*bid, k0+1; waves split h; no hot-loop syncs
__global__ __launch_bounds__(512) void k_main(const float* __restrict__ t2,
                                              const float* __restrict__ Tt,
                                              const float* __restrict__ x,
                                              const float* __restrict__ LC,
                                              const float* __restrict__ a,
                                              const float* __restrict__ Oxy,
                                              float* __restrict__ out) {
    __shared__ float red[8 * 2 * NB];      // 4 KB cross-wave reduce
    int tid = threadIdx.x;
    int lane = tid & 63, wv = tid >> 6;    // lane<->b, 8 waves split h
    int k0 = __builtin_amdgcn_readfirstlane(blockIdx.x * 2);
    float ms0 = -x[(size_t)lane * NN + k0];        // -x[b][k0] (L2-resident gather)
    float ms1 = -x[(size_t)lane * NN + k0 + 1];
    const float* r0 = t2 + (size_t)k0 * NH;        // wave-uniform rows -> s_load
    const float* r1 = r0 + NH;

    float lp0 = 0.f, lp1 = 0.f;
    int hb = wv * 256;                     // this wave's h-range [hb, hb+256)
    for (int h0 = hb; h0 < hb + 256; h0 += 32) {
        float p0 = 1.f, p1 = 1.f;
#pragma unroll
        for (int hh = 0; hh < 32; hh++) {
            int h = h0 + hh;
            float T = Tt[(size_t)h * NB + lane];   // coalesced 256B/wave, L2-hit
            p0 *= fmaf(r0[h] * T, ms0, 1.0f);      // 1 - s*T*tanh(2W)
            p1 *= fmaf(r1[h] * T, ms1, 1.0f);
        }
        lp0 += __logf(p0);                 // |ln u| small -> 32-chunk product safe
        lp1 += __logf(p1);
    }
    red[(wv * 2 + 0) * NB + lane] = lp0;
    red[(wv * 2 + 1) * NB + lane] = lp1;
    __syncthreads();
    if (tid < NB) {                        // wave 0 finalizes; lane = b
        float d0 = LC[k0]     + 2.0f * ms0 * a[k0];       // -2 x a = +2 ms a
        float d1 = LC[k0 + 1] + 2.0f * ms1 * a[k0 + 1];
#pragma unroll
        for (int w2 = 0; w2 < 8; w2++) {
            d0 += red[(w2 * 2 + 0) * NB + tid];
            d1 += red[(w2 * 2 + 1) * NB + tid];
        }
        float c = Oxy[k0] * __expf(d0) + Oxy[k0 + 1] * __expf(d1);
        atomicAdd(&out[tid], c);           // 256 adds per address, device-scope
    }
}

extern "C" void kernel_launch(void* const* d_in, const int* in_sizes, int n_in,
                              void* d_out, int out_size, void* d_ws, size_t ws_size,
                              hipStream_t stream) {
    const float* x    = (const float*)d_in[0];
    const float* W    = (const float*)d_in[1];
    const float* bvec = (const float*)d_in[2];
    const float* a    = (const float*)d_in[3];
    const float* Oxy  = (const float*)d_in[4];
    float* out = (float*)d_out;

    float* ws = (float*)d_ws;
    float* t2 = ws + OFF_T2;
    float* LC = ws + OFF_LC;
    float* Tt = ws + OFF_TT;

    k_prep<<<NN + 128, 512, 0, stream>>>(W, x, bvec, t2, LC, Tt, out);
    k_main<<<NN / 2, 512, 0, stream>>>(t2, Tt, x, LC, a, Oxy, out);
}